// Round 5
// baseline (218.591 us; speedup 1.0000x reference)
//
#include <hip/hip_runtime.h>
#include <math.h>

#define BB 32
#define AA 8400
#define MM 32
#define NCC 80
#define TOPK 13
#define CAP 1024        // max in-gts anchors per gt: E[max] ~820, >7 sigma to exceed 1024
#define NW (AA / 32 + 1)
#define T12 512         // k12 block size: 8 waves -> 2x latency hiding vs 256
#define FGCAP 512       // fg anchors per batch <= 32*13 = 416 < 512

typedef float nfloat4 __attribute__((ext_vector_type(4)));   // native vec for nontemporal builtins

// ---------------------------------------------------------------- wave argmax (64-lane, lowest index on tie)
__device__ __forceinline__ void wave_argmax(float& v, int& i) {
    #pragma unroll
    for (int off = 32; off > 0; off >>= 1) {
        float ov = __shfl_xor(v, off, 64);
        int oi = __shfl_xor(i, off, 64);
        if (ov > v || (ov == v && oi < i)) { v = ov; i = oi; }
    }
}

// ---------------------------------------------------------------- K12: compaction + top-13 -> sel lists (+carried ov/am)
__global__ __launch_bounds__(T12, 8) void k12_topk(
        const float* __restrict__ pd_scores, const float* __restrict__ pd_bboxes,
        const float* __restrict__ anc, const int* __restrict__ gt_labels,
        const float* __restrict__ gt_bboxes, const float* __restrict__ mask_gt,
        int* __restrict__ sel_idx, float* __restrict__ sel_ov, float* __restrict__ sel_am,
        float* __restrict__ pos_am, float* __restrict__ pos_ov,
        int* __restrict__ fgcnt) {
    __shared__ float lval[CAP];
    __shared__ int   lidx[CAP];
    __shared__ float oval[CAP];          // overlap per candidate (fallback path reads)
    __shared__ unsigned int bmask[NW];   // positivity bitmask (val>0)
    __shared__ float lw[8][TOPK];        // per-wave top-13 value
    __shared__ int   li[8][TOPK];        // per-wave top-13 index
    __shared__ float lo[8][TOPK];        // per-wave top-13 overlap
    __shared__ int   wsum[8];
    __shared__ int   s_p, s_sel;
    const float eps = 1e-7f;
    // no XCD swizzle: default round-robin balances working blocks across XCDs
    // (swizzle pinned each batch to one XCD -> per-XCD work = sum of 4 x U(1,32), +40% tail)
    int bm = blockIdx.x;
    int b = bm >> 5;
    int m = bm & 31;
    int tid = threadIdx.x;
    int lane = tid & 63;
    int wid = tid >> 6;
    if (tid == 0) pos_am[bm] = 0.f;
    if (tid == 1) pos_ov[bm] = 0.f;
    if (tid == 2) s_p = 0;
    if (tid == 3) s_sel = 0;
    if (m == 0 && tid == 4) fgcnt[b] = 0;        // ws poisoned每call: zero the fg-list counter
    if (tid < 16) sel_idx[bm * 16 + tid] = -1;   // -1 = empty slot
    if (!(mask_gt[bm] > 0.f)) return;  // mg=false row -> no selections

    for (int i = tid; i < NW; i += T12) bmask[i] = 0u;
    float4 g = reinterpret_cast<const float4*>(gt_bboxes)[bm];

    // ---- pass 1: streaming in-gts test, bits into a register (9 loads/thread, all in flight)
    const float4* anc4 = reinterpret_cast<const float4*>(anc);   // 4200 entries, 2 anchors each
    unsigned long long bits = 0ull;
    int c_t = 0;
    #pragma unroll
    for (int j = 0; j < 9; j++) {
        int e = tid + (j << 9);
        if (e < 4200) {
            float4 an = anc4[e];   // anchor 2e=(x,y), anchor 2e+1=(z,w)
            float d0 = fminf(fminf(an.x - g.x, an.y - g.y), fminf(g.z - an.x, g.w - an.y));
            float d1 = fminf(fminf(an.z - g.x, an.w - g.y), fminf(g.z - an.z, g.w - an.w));
            if (d0 > 1e-9f) { bits |= 1ull << (2 * j);     c_t++; }
            if (d1 > 1e-9f) { bits |= 1ull << (2 * j + 1); c_t++; }
        }
    }
    // ---- block prefix sum of c_t (wave scan + 8-way combine)
    int x = c_t;
    #pragma unroll
    for (int off = 1; off < 64; off <<= 1) {
        int y = __shfl_up(x, off, 64);
        if (lane >= off) x += y;
    }
    if (lane == 63) wsum[wid] = x;
    __syncthreads();
    int base = 0;
    #pragma unroll
    for (int w = 0; w < 8; w++) if (w < wid) base += wsum[w];
    int n_c = 0;
    #pragma unroll
    for (int w = 0; w < 8; w++) n_c += wsum[w];
    n_c = min(n_c, CAP);
    // ---- pass 2: scatter indices from register bitmask
    {
        int o = base + x - c_t;   // exclusive offset
        unsigned long long mm_ = bits;
        while (mm_) {
            int k = __builtin_ctzll(mm_);
            mm_ &= mm_ - 1ull;
            int i = 2 * tid + 1024 * (k >> 1) + (k & 1);
            if (o < CAP) lidx[o] = i;
            o++;
        }
    }
    for (int s = n_c + tid; s < CAP; s += T12) { lval[s] = -1.f; lidx[s] = AA; }
    __syncthreads();

    // ---- phase B: CIoU + score gather only for compacted anchors.
    // 2 slots/thread, all gathers issued upfront, results kept in REGISTERS for top-k.
    float w1 = g.z - g.x, h1 = g.w - g.y + eps;
    float atg = atanf(w1 / h1);
    float w1h1 = w1 * h1;
    float sgx = g.x + g.z, sgy = g.y + g.w;
    int lab = gt_labels[bm];
    const float4* pbb = reinterpret_cast<const float4*>(pd_bboxes) + (long)b * AA;
    const float* scp = pd_scores + (long)b * AA * NCC + lab;
    float rv0 = -1.f, rv1 = -1.f;        // register slot values (selection key)
    float rov0 = 0.f, rov1 = 0.f;        // register slot overlaps
    int   ri0 = AA,   ri1 = AA;          // register slot anchor indices
    {
        int    ci0, ci1;
        float4 pb0, pb1;
        float  sc0, sc1;
        ci0 = (tid < n_c)        ? lidx[tid]        : -1;
        ci1 = (tid + T12 < n_c)  ? lidx[tid + T12]  : -1;
        if (ci0 >= 0) { pb0 = pbb[ci0]; sc0 = scp[(long)ci0 * NCC]; ri0 = ci0; }
        if (ci1 >= 0) { pb1 = pbb[ci1]; sc1 = scp[(long)ci1 * NCC]; ri1 = ci1; }
        int pcnt = 0;
        #define CIOU_SLOT(CI, PB, SC, RV, ROV, S)                                     \
            if (CI >= 0) {                                                            \
                float w2 = PB.z - PB.x, h2 = PB.w - PB.y + eps;                       \
                float iw = fmaxf(fminf(g.z, PB.z) - fmaxf(g.x, PB.x), 0.f);           \
                float ih = fmaxf(fminf(g.w, PB.w) - fmaxf(g.y, PB.y), 0.f);           \
                float inter = iw * ih;                                                \
                float uni = w1h1 + w2 * h2 - inter + eps;                             \
                float iou = inter / uni;                                              \
                float cw = fmaxf(g.z, PB.z) - fminf(g.x, PB.x);                       \
                float ch = fmaxf(g.w, PB.w) - fminf(g.y, PB.y);                       \
                float c2 = cw * cw + ch * ch + eps;                                   \
                float dx = PB.x + PB.z - sgx, dy = PB.y + PB.w - sgy;                 \
                float rho2 = (dx * dx + dy * dy) * 0.25f;                             \
                float dv = atanf(w2 / h2) - atg;                                      \
                float v = 0.4052847345693511f * dv * dv;                              \
                float alpha = v / (v - iou + (1.0f + eps));                           \
                float cv = iou - (rho2 / c2 + v * alpha);                             \
                float ov = fmaxf(cv, 0.f);                                            \
                float o2 = ov * ov;                                                   \
                float val = SC * o2 * o2 * o2;   /* ALPHA=1, BETA=6 */                \
                bool pos = val > 0.f;                                                 \
                RV = pos ? val : -1.f;                                                \
                ROV = ov;                                                             \
                lval[S] = RV;                                                         \
                oval[S] = ov;                                                         \
                if (pos) { atomicOr(&bmask[CI >> 5], 1u << (CI & 31)); pcnt++; }      \
            }
        CIOU_SLOT(ci0, pb0, sc0, rv0, rov0, tid)
        CIOU_SLOT(ci1, pb1, sc1, rv1, rov1, tid + T12)
        #undef CIOU_SLOT
        #pragma unroll
        for (int off = 32; off > 0; off >>= 1) pcnt += __shfl_xor(pcnt, off, 64);
        if (lane == 0) atomicAdd(&s_p, pcnt);
    }
    __syncthreads();
    int p = s_p;

    if (p >= TOPK) {
        // ---- per-wave top-13 over 2 register slots/lane: pure shfl, ZERO barriers, ZERO LDS reads
        for (int k = 0; k < TOPK; k++) {
            float bv = rv0; int bi = ri0;
            if (rv1 > bv || (rv1 == bv && ri1 < bi)) { bv = rv1; bi = ri1; }
            wave_argmax(bv, bi);
            // unique owner records overlap + invalidates (anchor indices unique across slots)
            if (ri0 == bi && bi < AA) { rv0 = -1.f; lo[wid][k] = rov0; }
            if (ri1 == bi && bi < AA) { rv1 = -1.f; lo[wid][k] = rov1; }
            if (lane == 0) { lw[wid][k] = bv; li[wid][k] = bi; }
        }
        __syncthreads();
        // ---- wave 0: merge 8x13=104 candidates (2/lane), 13 shfl rounds, ZERO barriers
        if (wid == 0) {
            float mv0 = -1.f, mv1 = -1.f, mo0 = 0.f, mo1 = 0.f;
            int mi0 = AA, mi1 = AA;
            int e0 = 2 * lane, e1 = 2 * lane + 1;
            if (e0 < 8 * TOPK) {
                int w = e0 / TOPK, k = e0 - w * TOPK;
                mv0 = lw[w][k]; mi0 = li[w][k]; mo0 = lo[w][k];
            }
            if (e1 < 8 * TOPK) {
                int w = e1 / TOPK, k = e1 - w * TOPK;
                mv1 = lw[w][k]; mi1 = li[w][k]; mo1 = lo[w][k];
            }
            for (int k = 0; k < TOPK; k++) {
                float bv = mv0; int bi = mi0;
                if (mv1 > bv || (mv1 == bv && mi1 < bi)) { bv = mv1; bi = mi1; }
                wave_argmax(bv, bi);
                if (mi0 == bi && mv0 > -1.f) {      // unique owner writes round-k winner
                    sel_idx[bm * 16 + k] = bi;
                    sel_am[bm * 16 + k] = mv0;
                    sel_ov[bm * 16 + k] = mo0;
                    mv0 = -1.f;
                } else if (mi1 == bi && mv1 > -1.f) {
                    sel_idx[bm * 16 + k] = bi;
                    sel_am[bm * 16 + k] = mv1;
                    sel_ov[bm * 16 + k] = mo1;
                    mv1 = -1.f;
                }
            }
        }
    } else {
        // ---- all p positives selected (append via LDS counter, <=13 hits) ...
        for (int s = tid; s < n_c; s += T12)
            if (lval[s] > 0.f) {
                int slot = atomicAdd(&s_sel, 1);
                sel_idx[bm * 16 + slot] = lidx[s];
                sel_ov[bm * 16 + slot] = oval[s];
                sel_am[bm * 16 + slot] = lval[s];
            }
        // ---- ... plus the 13-p lowest-index zero-valued anchors (ballot windows, wave 0)
        if (wid == 0) {
            int need = TOPK - p;
            for (int base_i = 0; need > 0 && base_i < AA; base_i += 64) {
                int i = base_i + lane;
                bool cand = (i < AA) && !((bmask[i >> 5] >> (i & 31)) & 1u);
                unsigned long long wm = __ballot(cand);
                int take = min(need, (int)__popcll(wm));
                if (cand && (int)__popcll(wm & ((1ull << lane) - 1ull)) < take) {
                    // selected by top_k regardless of in-gts; in-gts mask applies after
                    float2 an = reinterpret_cast<const float2*>(anc)[i];
                    float dmin = fminf(fminf(an.x - g.x, an.y - g.y), fminf(g.z - an.x, g.w - an.y));
                    if (dmin > 1e-9f) {
                        // exact overlap for zero-val filler (sc==0 corner: ov may be >0)
                        float4 pb = pbb[i];
                        float w2 = pb.z - pb.x, h2 = pb.w - pb.y + eps;
                        float iw = fmaxf(fminf(g.z, pb.z) - fmaxf(g.x, pb.x), 0.f);
                        float ih = fmaxf(fminf(g.w, pb.w) - fmaxf(g.y, pb.y), 0.f);
                        float inter = iw * ih;
                        float uni = w1h1 + w2 * h2 - inter + eps;
                        float iou = inter / uni;
                        float cw = fmaxf(g.z, pb.z) - fminf(g.x, pb.x);
                        float ch = fmaxf(g.w, pb.w) - fminf(g.y, pb.y);
                        float c2 = cw * cw + ch * ch + eps;
                        float dx = pb.x + pb.z - sgx, dy = pb.y + pb.w - sgy;
                        float rho2 = (dx * dx + dy * dy) * 0.25f;
                        float dv = atanf(w2 / h2) - atg;
                        float v = 0.4052847345693511f * dv * dv;
                        float alpha = v / (v - iou + (1.0f + eps));
                        float ov = fmaxf(iou - (rho2 / c2 + v * alpha), 0.f);
                        int slot = atomicAdd(&s_sel, 1);
                        sel_idx[bm * 16 + slot] = i;
                        sel_ov[bm * 16 + slot] = ov;
                        sel_am[bm * 16 + slot] = 0.f;   // filler is never a positive
                    }
                }
                need -= take;
            }
        }
    }
}

// ---------------------------------------------------------------- K3: per-anchor column resolve + zero-fill scores + fg-list append
__global__ __launch_bounds__(256) void k3_resolve(
        const float* __restrict__ pd_scores, const float* __restrict__ pd_bboxes,
        const float* __restrict__ anc, const int* __restrict__ gt_labels,
        const float* __restrict__ gt_bboxes, const float* __restrict__ mask_gt,
        const int* __restrict__ sel_idx, const float* __restrict__ sel_ov,
        const float* __restrict__ sel_am,
        float* __restrict__ pos_am, float* __restrict__ pos_ov,
        float* __restrict__ out_bbox, float* __restrict__ out_fg,
        float* __restrict__ out_scores,
        int* __restrict__ fgcnt, int2* __restrict__ fglist) {
    __shared__ float sg[MM][8];   // x1,y1,x2,y2,w1h1,atg,sgx,sgy
    __shared__ int slab[MM];
    __shared__ int smg[MM];
    __shared__ unsigned int selcol[256];   // per-anchor m-bitmask for this 256-anchor chunk
    __shared__ float sov[256];             // carried overlap (valid iff fg==1)
    __shared__ float sam[256];             // carried align metric (valid iff fg==1)
    const float eps = 1e-7f;
    int b = blockIdx.y;
    int tid = threadIdx.x;
    if (tid < MM) {
        int gm = b * MM + tid;
        float4 g = reinterpret_cast<const float4*>(gt_bboxes)[gm];
        float w1 = g.z - g.x, h1 = g.w - g.y + eps;
        sg[tid][0] = g.x; sg[tid][1] = g.y; sg[tid][2] = g.z; sg[tid][3] = g.w;
        sg[tid][4] = w1 * h1;
        sg[tid][5] = atanf(w1 / h1);
        sg[tid][6] = g.x + g.z;
        sg[tid][7] = g.y + g.w;
        int lb = gt_labels[gm]; if (lb < 0) lb = 0;
        slab[tid] = lb;
        smg[tid] = mask_gt[gm] > 0.f ? 1 : 0;
    }
    selcol[tid] = 0u;
    __syncthreads();
    int a0 = blockIdx.x * 256;
    // build the column mask from this batch's 32 lists (512 entries, 2 iters)
    const int* sl = sel_idx + b * MM * 16;
    #pragma unroll
    for (int t = tid; t < MM * 16; t += 256) {
        int e = sl[t];
        if (e >= a0 && e < a0 + 256) {
            atomicOr(&selcol[e - a0], 1u << (t >> 4));
            sov[e - a0] = sel_ov[b * MM * 16 + t];   // single writer iff fg==1 (only path that reads it)
            sam[e - a0] = sel_am[b * MM * 16 + t];
        }
    }
    __syncthreads();
    // ---- zero-fill this chunk's out_scores (coalesced nontemporal); k4 scatters the <=416 nonzeros
    {
        nfloat4 z = {0.f, 0.f, 0.f, 0.f};
        nfloat4* outs4 = reinterpret_cast<nfloat4*>(out_scores) + ((long)b * AA + a0) * (NCC / 4);
        int lim = (AA - a0 < 256 ? AA - a0 : 256) * (NCC / 4);
        for (int idx = tid; idx < lim; idx += 256)
            __builtin_nontemporal_store(z, outs4 + idx);
    }
    int a = a0 + tid;
    if (a >= AA) return;
    int g = b * AA + a;
    unsigned int sel = selcol[tid];
    int fg = __popc(sel);

    int tg = 0; bool fgo = false; float ovt = 0.f; float amv = 0.f;
    if (fg == 1) {
        // single positive: values carried from k12 — no recompute, no gathers
        tg = __ffs(sel) - 1;
        ovt = sov[tid];
        amv = sam[tid];
        fgo = true;
    } else if (fg > 1) {
        // multi-assigned: replace column with first-occurrence argmax of masked overlaps
        float ax = anc[a * 2], ay = anc[a * 2 + 1];
        float4 pb = reinterpret_cast<const float4*>(pd_bboxes)[g];
        float w2 = pb.z - pb.x, h2 = pb.w - pb.y + eps;
        float atp = atanf(w2 / h2);
        float w2h2 = w2 * h2;
        float spx = pb.x + pb.z, spy = pb.y + pb.w;
        float bestov = -1.f; int bestm = 0;
        for (int mm = 0; mm < MM; mm++) {
            float gx1 = sg[mm][0], gy1 = sg[mm][1], gx2 = sg[mm][2], gy2 = sg[mm][3];
            float dmin = fminf(fminf(ax - gx1, ay - gy1), fminf(gx2 - ax, gy2 - ay));
            float ov = 0.f;
            if ((dmin > 1e-9f) && smg[mm]) {
                float iw = fmaxf(fminf(gx2, pb.z) - fmaxf(gx1, pb.x), 0.f);
                float ih = fmaxf(fminf(gy2, pb.w) - fmaxf(gy1, pb.y), 0.f);
                float inter = iw * ih;
                float uni = sg[mm][4] + w2h2 - inter + eps;
                float iou = inter / uni;
                float cw = fmaxf(gx2, pb.z) - fminf(gx1, pb.x);
                float ch = fmaxf(gy2, pb.w) - fminf(gy1, pb.y);
                float c2 = cw * cw + ch * ch + eps;
                float dx = spx - sg[mm][6], dy = spy - sg[mm][7];
                float rho2 = (dx * dx + dy * dy) * 0.25f;
                float dv = atp - sg[mm][5];
                float v = 0.4052847345693511f * dv * dv;
                float alpha = v / (v - iou + (1.0f + eps));
                ov = fmaxf(iou - (rho2 / c2 + v * alpha), 0.f);
            }
            if (ov > bestov) { bestov = ov; bestm = mm; }
        }
        tg = bestm; ovt = bestov;
        float sc = pd_scores[(long)g * NCC + slab[tg]];
        float o2 = ovt * ovt;
        amv = sc * o2 * o2 * o2;
        fgo = true;
    }

    nfloat4 gb = {sg[tg][0], sg[tg][1], sg[tg][2], sg[tg][3]};
    __builtin_nontemporal_store(gb, reinterpret_cast<nfloat4*>(out_bbox) + g);
    out_fg[g] = fgo ? 1.f : 0.f;
    if (fgo) {
        atomicMax((int*)&pos_am[b * MM + tg], __float_as_int(amv));   // non-negative floats: int order == float order
        atomicMax((int*)&pos_ov[b * MM + tg], __float_as_int(ovt));
        // append to compact fg list: a(14b) | tg(5b) | lab(7b)
        int slot = atomicAdd(&fgcnt[b], 1);
        fglist[b * FGCAP + slot] = make_int2(a | (tg << 14) | (slab[tg] << 19), __float_as_int(amv));
    }
}

// ---------------------------------------------------------------- K4: scatter the <=416 nonzero normalized scores per batch
__global__ __launch_bounds__(256) void k4_scatter(
        const int* __restrict__ fgcnt, const int2* __restrict__ fglist,
        const float* __restrict__ pos_am, const float* __restrict__ pos_ov,
        float* __restrict__ out_scores) {
    int b = blockIdx.x;
    int n = fgcnt[b];
    for (int t = threadIdx.x; t < n; t += 256) {
        int2 e = fglist[b * FGCAP + t];
        int a   = e.x & 16383;
        int tg  = (e.x >> 14) & 31;
        int lab = (e.x >> 19) & 127;
        int bmi = b * MM + tg;
        float nv = (__int_as_float(e.y) * pos_ov[bmi]) / (pos_am[bmi] + 1e-9f);
        out_scores[((long)b * AA + a) * NCC + lab] = nv;
    }
}

// ---------------------------------------------------------------- launch
extern "C" void kernel_launch(void* const* d_in, const int* in_sizes, int n_in,
                              void* d_out, int out_size, void* d_ws, size_t ws_size,
                              hipStream_t stream) {
    const float* pd_scores = (const float*)d_in[0];
    const float* pd_bboxes = (const float*)d_in[1];
    const float* anc       = (const float*)d_in[2];
    const int*   gt_labels = (const int*)d_in[3];
    const float* gt_bboxes = (const float*)d_in[4];
    const float* mask_gt   = (const float*)d_in[5];

    const long nBA = (long)BB * AA;

    char* ws = (char*)d_ws;
    int*   sel_idx = (int*)ws;                  ws += (long)BB * MM * 16 * 4;
    float* sel_ov  = (float*)ws;                ws += (long)BB * MM * 16 * 4;
    float* sel_am  = (float*)ws;                ws += (long)BB * MM * 16 * 4;
    float* pos_am  = (float*)ws;                ws += BB * MM * 4;
    float* pos_ov  = (float*)ws;                ws += BB * MM * 4;
    int*   fgcnt   = (int*)ws;                  ws += BB * 4;
    int2*  fglist  = (int2*)ws;                 ws += (long)BB * FGCAP * 8;

    float* out_bbox   = (float*)d_out;            // B*A*4
    float* out_scores = out_bbox + nBA * 4;       // B*A*NC
    float* out_fg     = out_scores + nBA * NCC;   // B*A

    k12_topk<<<BB * MM, T12, 0, stream>>>(pd_scores, pd_bboxes, anc, gt_labels,
                                          gt_bboxes, mask_gt, sel_idx, sel_ov, sel_am,
                                          pos_am, pos_ov, fgcnt);
    dim3 g3((AA + 255) / 256, BB);
    k3_resolve<<<g3, 256, 0, stream>>>(pd_scores, pd_bboxes, anc, gt_labels,
                                       gt_bboxes, mask_gt, sel_idx, sel_ov, sel_am,
                                       pos_am, pos_ov, out_bbox, out_fg, out_scores,
                                       fgcnt, fglist);
    k4_scatter<<<BB, 256, 0, stream>>>(fgcnt, fglist, pos_am, pos_ov, out_scores);
}

// Round 6
// 188.560 us; speedup vs baseline: 1.1593x; 1.1593x over previous
//
#include <hip/hip_runtime.h>
#include <math.h>

#define BB 32
#define AA 8400
#define MM 32
#define NCC 80
#define TOPK 13
#define CAP 1024        // max in-gts anchors per gt: E[max] ~820, >7 sigma to exceed 1024
#define NW (AA / 32 + 1)

typedef float nfloat4 __attribute__((ext_vector_type(4)));   // native vec for nontemporal builtins

// ---------------------------------------------------------------- wave argmax (64-lane, lowest index on tie)
__device__ __forceinline__ void wave_argmax(float& v, int& i) {
    #pragma unroll
    for (int off = 32; off > 0; off >>= 1) {
        float ov = __shfl_xor(v, off, 64);
        int oi = __shfl_xor(i, off, 64);
        if (ov > v || (ov == v && oi < i)) { v = ov; i = oi; }
    }
}

// ---------------------------------------------------------------- K12: compaction + top-13 -> sel_idx list (no global atomics)
__global__ __launch_bounds__(256) void k12_topk(
        const float* __restrict__ pd_scores, const float* __restrict__ pd_bboxes,
        const float* __restrict__ anc, const int* __restrict__ gt_labels,
        const float* __restrict__ gt_bboxes, const float* __restrict__ mask_gt,
        int* __restrict__ sel_idx, float* __restrict__ pos_am, float* __restrict__ pos_ov) {
    __shared__ float lval[CAP];
    __shared__ int   lidx[CAP];
    __shared__ unsigned int bmask[NW];   // positivity bitmask (val>0)
    __shared__ float wv[4];
    __shared__ int   wi[4];
    __shared__ int   wsum[4];
    __shared__ int   s_p, s_sel;
    const float eps = 1e-7f;
    int bm = blockIdx.x;
    int b = bm >> 5;                 // MM = 32
    int tid = threadIdx.x;
    int lane = tid & 63;
    int wid = tid >> 6;
    if (tid == 0) pos_am[bm] = 0.f;
    if (tid == 1) pos_ov[bm] = 0.f;
    if (tid == 2) s_p = 0;
    if (tid == 3) s_sel = 0;
    if (tid < 16) sel_idx[bm * 16 + tid] = -1;   // ws poisoned every call; -1 = empty slot
    if (!(mask_gt[bm] > 0.f)) return;  // mg=false row -> no selections (tk_idx->0, counts=13->0)

    for (int i = tid; i < NW; i += 256) bmask[i] = 0u;
    float4 g = reinterpret_cast<const float4*>(gt_bboxes)[bm];

    // ---- pass 1: streaming in-gts test, bits into a register (no cross-iteration deps)
    const float4* anc4 = reinterpret_cast<const float4*>(anc);   // 4200 entries, 2 anchors each
    unsigned long long bits = 0ull;
    int c_t = 0;
    #pragma unroll
    for (int j = 0; j < 17; j++) {
        int e = tid + (j << 8);
        if (e < 4200) {
            float4 an = anc4[e];   // anchor 2e=(x,y), anchor 2e+1=(z,w)
            float d0 = fminf(fminf(an.x - g.x, an.y - g.y), fminf(g.z - an.x, g.w - an.y));
            float d1 = fminf(fminf(an.z - g.x, an.w - g.y), fminf(g.z - an.z, g.w - an.w));
            if (d0 > 1e-9f) { bits |= 1ull << (2 * j);     c_t++; }
            if (d1 > 1e-9f) { bits |= 1ull << (2 * j + 1); c_t++; }
        }
    }
    // ---- block prefix sum of c_t (wave scan + 4-way combine)
    int x = c_t;
    #pragma unroll
    for (int off = 1; off < 64; off <<= 1) {
        int y = __shfl_up(x, off, 64);
        if (lane >= off) x += y;
    }
    if (lane == 63) wsum[wid] = x;
    __syncthreads();
    int base = 0;
    #pragma unroll
    for (int w = 0; w < 4; w++) if (w < wid) base += wsum[w];
    int n_c = min(wsum[0] + wsum[1] + wsum[2] + wsum[3], CAP);
    // ---- pass 2: scatter indices from register bitmask
    {
        int o = base + x - c_t;   // exclusive offset
        unsigned long long mm_ = bits;
        while (mm_) {
            int k = __builtin_ctzll(mm_);
            mm_ &= mm_ - 1ull;
            int i = 2 * tid + 512 * (k >> 1) + (k & 1);
            if (o < CAP) lidx[o] = i;
            o++;
        }
    }
    for (int s = n_c + tid; s < CAP; s += 256) { lval[s] = -1.f; lidx[s] = AA; }
    __syncthreads();

    // ---- phase B: CIoU + score gather only for compacted anchors
    float w1 = g.z - g.x, h1 = g.w - g.y + eps;
    float atg = atanf(w1 / h1);
    float w1h1 = w1 * h1;
    float sgx = g.x + g.z, sgy = g.y + g.w;
    int lab = gt_labels[bm];
    const float4* pbb = reinterpret_cast<const float4*>(pd_bboxes) + (long)b * AA;
    const float* scp = pd_scores + (long)b * AA * NCC + lab;
    int nit = (n_c + 255) >> 8;
    for (int it = 0; it < nit; it++) {
        int s = (it << 8) + tid;
        bool pos = false;
        if (s < n_c) {
            int i = lidx[s];
            float4 pb = pbb[i];
            float sc = scp[(long)i * NCC];
            float w2 = pb.z - pb.x, h2 = pb.w - pb.y + eps;
            float iw = fmaxf(fminf(g.z, pb.z) - fmaxf(g.x, pb.x), 0.f);
            float ih = fmaxf(fminf(g.w, pb.w) - fmaxf(g.y, pb.y), 0.f);
            float inter = iw * ih;
            float uni = w1h1 + w2 * h2 - inter + eps;
            float iou = inter / uni;
            float cw = fmaxf(g.z, pb.z) - fminf(g.x, pb.x);
            float ch = fmaxf(g.w, pb.w) - fminf(g.y, pb.y);
            float c2 = cw * cw + ch * ch + eps;
            float dx = pb.x + pb.z - sgx, dy = pb.y + pb.w - sgy;
            float rho2 = (dx * dx + dy * dy) * 0.25f;
            float dv = atanf(w2 / h2) - atg;
            float v = 0.4052847345693511f * dv * dv;
            float alpha = v / (v - iou + (1.0f + eps));
            float cv = iou - (rho2 / c2 + v * alpha);
            float ov = fmaxf(cv, 0.f);
            float o2 = ov * ov;
            float val = sc * o2 * o2 * o2;   // ALPHA=1, BETA=6
            pos = val > 0.f;
            lval[s] = pos ? val : -1.f;      // in-gts but zero metric: not a positive candidate
            if (pos) atomicOr(&bmask[i >> 5], 1u << (i & 31));
        }
        unsigned long long pm = __ballot(pos);
        if (lane == 0) atomicAdd(&s_p, (int)__popcll(pm));
    }
    __syncthreads();
    int p = s_p;

    if (p >= TOPK) {
        // ---- 13 extraction rounds, register-resident (4 slots/thread), no global ops inside
        float v0 = lval[tid], v1 = lval[tid + 256], v2 = lval[tid + 512], v3 = lval[tid + 768];
        int   i0 = lidx[tid], i1 = lidx[tid + 256], i2 = lidx[tid + 512], i3 = lidx[tid + 768];
        int mysel = -1;
        for (int k = 0; k < TOPK; k++) {
            float bv = v0; int bi = i0;
            if (v1 > bv || (v1 == bv && i1 < bi)) { bv = v1; bi = i1; }
            if (v2 > bv || (v2 == bv && i2 < bi)) { bv = v2; bi = i2; }
            if (v3 > bv || (v3 == bv && i3 < bi)) { bv = v3; bi = i3; }
            wave_argmax(bv, bi);
            if (lane == 0) { wv[wid] = bv; wi[wid] = bi; }
            __syncthreads();
            float gv = wv[0]; int gi = wi[0];
            #pragma unroll
            for (int w = 1; w < 4; w++) {
                float ov = wv[w]; int oi = wi[w];
                if (ov > gv || (ov == gv && oi < gi)) { gv = ov; gi = oi; }
            }
            if (tid == k) mysel = gi;           // thread k owns round-k winner
            if (i0 == gi) v0 = -1.f;            // indices are unique: exact ownership
            if (i1 == gi) v1 = -1.f;
            if (i2 == gi) v2 = -1.f;
            if (i3 == gi) v3 = -1.f;
            __syncthreads();
        }
        if (tid < TOPK) sel_idx[bm * 16 + tid] = mysel;   // plain stores, no atomics
    } else {
        // ---- all p positives selected (append via LDS counter, <=13 hits) ...
        for (int s = tid; s < n_c; s += 256)
            if (lval[s] > 0.f) {
                int slot = atomicAdd(&s_sel, 1);
                sel_idx[bm * 16 + slot] = lidx[s];
            }
        // ---- ... plus the 13-p lowest-index zero-valued anchors (ballot windows, wave 0)
        if (wid == 0) {
            int need = TOPK - p;
            for (int base_i = 0; need > 0 && base_i < AA; base_i += 64) {
                int i = base_i + lane;
                bool cand = (i < AA) && !((bmask[i >> 5] >> (i & 31)) & 1u);
                unsigned long long wm = __ballot(cand);
                int take = min(need, (int)__popcll(wm));
                if (cand && (int)__popcll(wm & ((1ull << lane) - 1ull)) < take) {
                    // selected by top_k regardless of in-gts; in-gts mask applies after
                    float2 an = reinterpret_cast<const float2*>(anc)[i];
                    float dmin = fminf(fminf(an.x - g.x, an.y - g.y), fminf(g.z - an.x, g.w - an.y));
                    if (dmin > 1e-9f) {
                        int slot = atomicAdd(&s_sel, 1);
                        sel_idx[bm * 16 + slot] = i;
                    }
                }
                need -= take;
            }
        }
    }
}

// ---------------------------------------------------------------- K3: per-anchor column resolve (mask from sel_idx lists)
__global__ __launch_bounds__(256) void k3_resolve(
        const float* __restrict__ pd_scores, const float* __restrict__ pd_bboxes,
        const float* __restrict__ anc, const int* __restrict__ gt_labels,
        const float* __restrict__ gt_bboxes, const float* __restrict__ mask_gt,
        const int* __restrict__ sel_idx,
        float* __restrict__ pos_am, float* __restrict__ pos_ov,
        float* __restrict__ out_bbox, float* __restrict__ out_fg,
        int2* __restrict__ meta) {
    __shared__ float sg[MM][8];   // x1,y1,x2,y2,w1h1,atg,sgx,sgy
    __shared__ int slab[MM];
    __shared__ int smg[MM];
    __shared__ unsigned int selcol[256];   // per-anchor m-bitmask for this 256-anchor chunk
    const float eps = 1e-7f;
    int b = blockIdx.y;
    int tid = threadIdx.x;
    if (tid < MM) {
        int gm = b * MM + tid;
        float4 g = reinterpret_cast<const float4*>(gt_bboxes)[gm];
        float w1 = g.z - g.x, h1 = g.w - g.y + eps;
        sg[tid][0] = g.x; sg[tid][1] = g.y; sg[tid][2] = g.z; sg[tid][3] = g.w;
        sg[tid][4] = w1 * h1;
        sg[tid][5] = atanf(w1 / h1);
        sg[tid][6] = g.x + g.z;
        sg[tid][7] = g.y + g.w;
        int lb = gt_labels[gm]; if (lb < 0) lb = 0;
        slab[tid] = lb;
        smg[tid] = mask_gt[gm] > 0.f ? 1 : 0;
    }
    selcol[tid] = 0u;
    __syncthreads();
    int a0 = blockIdx.x * 256;
    // build the column mask from this batch's 32 lists (512 entries, 2 iters)
    const int* sl = sel_idx + b * MM * 16;
    #pragma unroll
    for (int t = tid; t < MM * 16; t += 256) {
        int e = sl[t];
        if (e >= a0 && e < a0 + 256) atomicOr(&selcol[e - a0], 1u << (t >> 4));
    }
    __syncthreads();
    int a = a0 + tid;
    if (a >= AA) return;
    int g = b * AA + a;
    unsigned int sel = selcol[tid];
    int fg = __popc(sel);

    int tg = 0; bool fgo = false; float ovt = 0.f;
    if (fg >= 1) {
        float ax = anc[a * 2], ay = anc[a * 2 + 1];
        float4 pb = reinterpret_cast<const float4*>(pd_bboxes)[g];
        float w2 = pb.z - pb.x, h2 = pb.w - pb.y + eps;
        float atp = atanf(w2 / h2);
        float w2h2 = w2 * h2;
        float spx = pb.x + pb.z, spy = pb.y + pb.w;
        fgo = true;
        if (fg == 1) {
            // single positive: masked overlap at that m (mask held by construction of sel_idx)
            tg = __ffs(sel) - 1;
            float gx1 = sg[tg][0], gy1 = sg[tg][1], gx2 = sg[tg][2], gy2 = sg[tg][3];
            float iw = fmaxf(fminf(gx2, pb.z) - fmaxf(gx1, pb.x), 0.f);
            float ih = fmaxf(fminf(gy2, pb.w) - fmaxf(gy1, pb.y), 0.f);
            float inter = iw * ih;
            float uni = sg[tg][4] + w2h2 - inter + eps;
            float iou = inter / uni;
            float cw = fmaxf(gx2, pb.z) - fminf(gx1, pb.x);
            float ch = fmaxf(gy2, pb.w) - fminf(gy1, pb.y);
            float c2 = cw * cw + ch * ch + eps;
            float dx = spx - sg[tg][6], dy = spy - sg[tg][7];
            float rho2 = (dx * dx + dy * dy) * 0.25f;
            float dv = atp - sg[tg][5];
            float v = 0.4052847345693511f * dv * dv;
            float alpha = v / (v - iou + (1.0f + eps));
            ovt = fmaxf(iou - (rho2 / c2 + v * alpha), 0.f);
        } else {
            // multi-assigned: replace column with first-occurrence argmax of masked overlaps
            float bestov = -1.f; int bestm = 0;
            for (int mm = 0; mm < MM; mm++) {
                float gx1 = sg[mm][0], gy1 = sg[mm][1], gx2 = sg[mm][2], gy2 = sg[mm][3];
                float dmin = fminf(fminf(ax - gx1, ay - gy1), fminf(gx2 - ax, gy2 - ay));
                float ov = 0.f;
                if ((dmin > 1e-9f) && smg[mm]) {
                    float iw = fmaxf(fminf(gx2, pb.z) - fmaxf(gx1, pb.x), 0.f);
                    float ih = fmaxf(fminf(gy2, pb.w) - fmaxf(gy1, pb.y), 0.f);
                    float inter = iw * ih;
                    float uni = sg[mm][4] + w2h2 - inter + eps;
                    float iou = inter / uni;
                    float cw = fmaxf(gx2, pb.z) - fminf(gx1, pb.x);
                    float ch = fmaxf(gy2, pb.w) - fminf(gy1, pb.y);
                    float c2 = cw * cw + ch * ch + eps;
                    float dx = spx - sg[mm][6], dy = spy - sg[mm][7];
                    float rho2 = (dx * dx + dy * dy) * 0.25f;
                    float dv = atp - sg[mm][5];
                    float v = 0.4052847345693511f * dv * dv;
                    float alpha = v / (v - iou + (1.0f + eps));
                    ov = fmaxf(iou - (rho2 / c2 + v * alpha), 0.f);
                }
                if (ov > bestov) { bestov = ov; bestm = mm; }
            }
            tg = bestm; ovt = bestov;
        }
    }

    nfloat4 gb = {sg[tg][0], sg[tg][1], sg[tg][2], sg[tg][3]};
    __builtin_nontemporal_store(gb, reinterpret_cast<nfloat4*>(out_bbox) + g);
    out_fg[g] = fgo ? 1.f : 0.f;
    float amv = 0.f;
    if (fgo) {
        float sc = pd_scores[(long)g * NCC + slab[tg]];
        float o2 = ovt * ovt;
        amv = sc * o2 * o2 * o2;          // ovt>0 implies mask held, so sc is the gathered score
        atomicMax((int*)&pos_am[b * MM + tg], __float_as_int(amv));   // non-negative floats: int order == float order
        atomicMax((int*)&pos_ov[b * MM + tg], __float_as_int(ovt));
    }
    meta[g] = make_int2(__float_as_int(amv), tg | (slab[tg] << 8) | ((fgo ? 1 : 0) << 16));
}

// ---------------------------------------------------------------- K4: norm + one-hot target_scores (nontemporal float4)
__global__ __launch_bounds__(256) void k4_scores(
        const int2* __restrict__ meta,
        const float* __restrict__ pos_am, const float* __restrict__ pos_ov,
        float* __restrict__ out_scores) {
    int g = blockIdx.x * 256 + threadIdx.x;
    const int NQ = NCC / 4;   // 20 float4 per (b,a)
    if (g >= BB * AA * NQ) return;
    int ba = g / NQ;
    int c0 = (g % NQ) * 4;
    nfloat4 o = {0.f, 0.f, 0.f, 0.f};
    int2 mt = meta[ba];
    int p = mt.y;
    if (p & (1 << 16)) {
        int tg = p & 31, lab = (p >> 8) & 127;
        int b = ba / AA;
        int bm = b * MM + tg;
        float nv = (__int_as_float(mt.x) * pos_ov[bm]) / (pos_am[bm] + 1e-9f);
        int d = lab - c0;
        if (d == 0) o.x = nv; else if (d == 1) o.y = nv;
        else if (d == 2) o.z = nv; else if (d == 3) o.w = nv;
    }
    __builtin_nontemporal_store(o, reinterpret_cast<nfloat4*>(out_scores) + g);
}

// ---------------------------------------------------------------- launch
extern "C" void kernel_launch(void* const* d_in, const int* in_sizes, int n_in,
                              void* d_out, int out_size, void* d_ws, size_t ws_size,
                              hipStream_t stream) {
    const float* pd_scores = (const float*)d_in[0];
    const float* pd_bboxes = (const float*)d_in[1];
    const float* anc       = (const float*)d_in[2];
    const int*   gt_labels = (const int*)d_in[3];
    const float* gt_bboxes = (const float*)d_in[4];
    const float* mask_gt   = (const float*)d_in[5];

    const long nBA = (long)BB * AA;

    char* ws = (char*)d_ws;
    int*   sel_idx = (int*)ws;                  ws += (long)BB * MM * 16 * 4;
    float* pos_am  = (float*)ws;                ws += BB * MM * 4;
    float* pos_ov  = (float*)ws;                ws += BB * MM * 4;
    int2*  meta    = (int2*)ws;                 ws += nBA * 8;

    float* out_bbox   = (float*)d_out;            // B*A*4
    float* out_scores = out_bbox + nBA * 4;       // B*A*NC
    float* out_fg     = out_scores + nBA * NCC;   // B*A

    k12_topk<<<BB * MM, 256, 0, stream>>>(pd_scores, pd_bboxes, anc, gt_labels,
                                          gt_bboxes, mask_gt, sel_idx, pos_am, pos_ov);
    dim3 g3((AA + 255) / 256, BB);
    k3_resolve<<<g3, 256, 0, stream>>>(pd_scores, pd_bboxes, anc, gt_labels,
                                       gt_bboxes, mask_gt, sel_idx, pos_am, pos_ov,
                                       out_bbox, out_fg, meta);
    long nS4 = nBA * (NCC / 4);
    k4_scores<<<(int)((nS4 + 255) / 256), 256, 0, stream>>>(meta, pos_am, pos_ov, out_scores);
}